// Round 1
// baseline (317.627 us; speedup 1.0000x reference)
//
#include <hip/hip_runtime.h>
#include <hip/hip_fp16.h>

// Problem constants (fixed by reference)
#define M_TOTAL 25088          // 128*14*14 rows
#define KDIM    384
#define NDIM    1536
#define NCHUNK  3              // hi*Whi + hi*Wlo + lo*Whi
#define KTOT    (KDIM*NCHUNK)  // 1152
#define BM      128
#define BN      128
#define BK      64
#define KSTEPS  (KTOT/BK)      // 18

typedef __attribute__((ext_vector_type(8))) _Float16 half8;
typedef __attribute__((ext_vector_type(4))) float   f32x4;

#define GLOAD_LDS16(g, l)                                                     \
  __builtin_amdgcn_global_load_lds(                                           \
      (const __attribute__((address_space(1))) unsigned int*)(g),             \
      (__attribute__((address_space(3))) unsigned int*)(l), 16, 0, 0)

// ---------------------------------------------------------------------------
// Kernel 1: W (384x1536 fp32, row-major W[c][f]) -> Bt fp16 [1536][1152]
//   Bt[f][c]        = hi(W[c][f])
//   Bt[f][384 + c]  = lo(W[c][f])
//   Bt[f][768 + c]  = hi(W[c][f])
// ---------------------------------------------------------------------------
__global__ __launch_bounds__(256) void prep_w(const float* __restrict__ W,
                                              _Float16* __restrict__ Bt) {
  int idx = blockIdx.x * 256 + threadIdx.x;   // idx = c*1536 + f (coalesced read)
  if (idx >= KDIM * NDIM) return;
  int c = idx / NDIM;
  int f = idx - c * NDIM;
  float w = W[idx];
  _Float16 hi = (_Float16)w;
  _Float16 lo = (_Float16)(w - (float)hi);
  _Float16* row = Bt + (size_t)f * KTOT;
  row[c]            = hi;
  row[KDIM + c]     = lo;
  row[2 * KDIM + c] = hi;
}

// ---------------------------------------------------------------------------
// Kernel 2: LayerNorm + fp16 hi/lo split.  One wave per row (384 cols).
// ---------------------------------------------------------------------------
__global__ __launch_bounds__(256) void ln_split(const float* __restrict__ x,
                                                const float* __restrict__ gamma,
                                                const float* __restrict__ beta,
                                                _Float16* __restrict__ Ahi,
                                                _Float16* __restrict__ Alo) {
  int wave = threadIdx.x >> 6;
  int lane = threadIdx.x & 63;
  int row  = blockIdx.x * 4 + wave;           // grid = 25088/4
  const float* xr = x + (size_t)row * KDIM;

  float v[6];
  float s = 0.f;
#pragma unroll
  for (int j = 0; j < 6; ++j) { v[j] = xr[j * 64 + lane]; s += v[j]; }
#pragma unroll
  for (int off = 32; off; off >>= 1) s += __shfl_xor(s, off);
  float mean = s * (1.f / 384.f);

  float s2 = 0.f;
#pragma unroll
  for (int j = 0; j < 6; ++j) { float d = v[j] - mean; s2 += d * d; }
#pragma unroll
  for (int off = 32; off; off >>= 1) s2 += __shfl_xor(s2, off);
  float rstd = rsqrtf(s2 * (1.f / 384.f) + 1e-5f);

  _Float16* hrow = Ahi + (size_t)row * KDIM;
  _Float16* lrow = Alo + (size_t)row * KDIM;
#pragma unroll
  for (int j = 0; j < 6; ++j) {
    int c = j * 64 + lane;
    float xn = (v[j] - mean) * rstd * gamma[c] + beta[c];
    _Float16 hi = (_Float16)xn;
    hrow[c] = hi;
    lrow[c] = (_Float16)(xn - (float)hi);
  }
}

// ---------------------------------------------------------------------------
// Kernel 3: fused split-GEMM (M=25088, N=1536, K=1152) + bias + erf-GELU.
// 128x128 tile, BK=64, 4 waves (2x2, 64x64 each), mfma_f32_16x16x32_f16.
// LDS: A[128][64] fp16 + B(cols)[128][64] fp16, 16B-slot XOR swizzle c^(r&7).
// global_load_lds (16B) with inverse-swizzled global source (rule #21).
// ---------------------------------------------------------------------------
__global__ __launch_bounds__(256) void gemm_fused(
    const _Float16* __restrict__ Ahi, const _Float16* __restrict__ Alo,
    const _Float16* __restrict__ Bt,  const float* __restrict__ bias,
    float* __restrict__ out) {
  __shared__ _Float16 Alds[BM * BK];   // [r][8 slots of 8 halves], slot swizzled
  __shared__ _Float16 Blds[BN * BK];

  const int tid  = threadIdx.x;
  const int lane = tid & 63;
  const int wave = tid >> 6;
  const int wr   = wave >> 1;          // 0..1  (rows)
  const int wc   = wave & 1;           // 0..1  (cols)

  // XCD-aware bijective swizzle: nwg = 196*12 = 2352 = 8*294
  int bidx = blockIdx.x;
  int swz  = (bidx & 7) * 294 + (bidx >> 3);
  int mb   = swz / (NDIM / BN);
  int nb   = swz - mb * (NDIM / BN);
  const int mrow0 = mb * BM;
  const int ncol0 = nb * BN;

  // --- staging constants (per-thread) ---
  const int rloc  = lane >> 3;                  // 0..7 row within 8-row group
  const int c_swz = (lane & 7) ^ rloc;          // inverse-swizzled 16B slot
  // A: wave instruction ii covers rows wave*32 + ii*8 .. +7
  size_t aoff[4], boff[4];
  _Float16* adst[4];
  _Float16* bdst[4];
#pragma unroll
  for (int ii = 0; ii < 4; ++ii) {
    int i = wave * 4 + ii;
    int r = i * 8 + rloc;
    aoff[ii] = (size_t)(mrow0 + r) * KDIM + (size_t)c_swz * 8;
    boff[ii] = (size_t)(ncol0 + r) * KTOT + (size_t)c_swz * 8;
    adst[ii] = Alds + i * 512;                  // 1024B per wave-instr
    bdst[ii] = Blds + i * 512;
  }

  // --- fragment read element offsets ---
  int ea[4][2], eb[4][2];
#pragma unroll
  for (int m = 0; m < 4; ++m) {
    int r = wr * 64 + m * 16 + (lane & 15);
    int rb = wc * 64 + m * 16 + (lane & 15);
#pragma unroll
    for (int k2 = 0; k2 < 2; ++k2) {
      int slot = k2 * 4 + (lane >> 4);
      ea[m][k2] = r  * 64 + ((slot ^ (r  & 7)) * 8);
      eb[m][k2] = rb * 64 + ((slot ^ (rb & 7)) * 8);
    }
  }

  f32x4 acc[4][4];
#pragma unroll
  for (int m = 0; m < 4; ++m)
#pragma unroll
    for (int n = 0; n < 4; ++n) acc[m][n] = (f32x4){0.f, 0.f, 0.f, 0.f};

  // --- K loop: 3 chunks x 6 steps of BK=64 ---
  for (int ch = 0; ch < 3; ++ch) {
    const _Float16* Asrc = (ch < 2) ? Ahi : Alo;
    for (int s6 = 0; s6 < 6; ++s6) {
      const int acol = s6 * BK;                 // within 0..383
      const int bcol = (ch * 6 + s6) * BK;      // within 0..1151

      __syncthreads();                          // prev compute done
#pragma unroll
      for (int ii = 0; ii < 4; ++ii) {
        GLOAD_LDS16(Asrc + aoff[ii] + acol, adst[ii]);
        GLOAD_LDS16(Bt   + boff[ii] + bcol, bdst[ii]);
      }
      __syncthreads();                          // compiler drains vmcnt(0)

      half8 af[2][4], bf[2][4];
#pragma unroll
      for (int m = 0; m < 4; ++m) {
#pragma unroll
        for (int k2 = 0; k2 < 2; ++k2) {
          af[k2][m] = *(const half8*)&Alds[ea[m][k2]];
          bf[k2][m] = *(const half8*)&Blds[eb[m][k2]];
        }
      }
#pragma unroll
      for (int k2 = 0; k2 < 2; ++k2)
#pragma unroll
        for (int m = 0; m < 4; ++m)
#pragma unroll
          for (int n = 0; n < 4; ++n)
            acc[m][n] = __builtin_amdgcn_mfma_f32_16x16x32_f16(
                af[k2][m], bf[k2][n], acc[m][n], 0, 0, 0);
    }
  }

  // --- epilogue: bias + exact GELU, fp32 store ---
#pragma unroll
  for (int n = 0; n < 4; ++n) {
    int col = ncol0 + wc * 64 + n * 16 + (lane & 15);
    float bv = bias[col];
#pragma unroll
    for (int m = 0; m < 4; ++m) {
      int row = mrow0 + wr * 64 + m * 16 + ((lane >> 4) << 2);
#pragma unroll
      for (int j = 0; j < 4; ++j) {
        float y = acc[m][n][j] + bv;
        float g = 0.5f * y * (1.f + erff(y * 0.70710678118654752f));
        out[(size_t)(row + j) * NDIM + col] = g;
      }
    }
  }
}

// ---------------------------------------------------------------------------
extern "C" void kernel_launch(void* const* d_in, const int* in_sizes, int n_in,
                              void* d_out, int out_size, void* d_ws, size_t ws_size,
                              hipStream_t stream) {
  const float* x     = (const float*)d_in[0];
  const float* gamma = (const float*)d_in[1];
  const float* beta  = (const float*)d_in[2];
  const float* W     = (const float*)d_in[3];
  const float* bias  = (const float*)d_in[4];
  float* out = (float*)d_out;

  // workspace layout (bytes)
  const size_t ahi_off = 0;
  const size_t alo_off = (size_t)M_TOTAL * KDIM * 2;             // 19,267,584
  const size_t bt_off  = alo_off * 2;                            // 38,535,168
  _Float16* Ahi = (_Float16*)((char*)d_ws + ahi_off);
  _Float16* Alo = (_Float16*)((char*)d_ws + alo_off);
  _Float16* Btd = (_Float16*)((char*)d_ws + bt_off);

  hipLaunchKernelGGL(prep_w, dim3((KDIM * NDIM + 255) / 256), dim3(256), 0,
                     stream, W, Btd);
  hipLaunchKernelGGL(ln_split, dim3(M_TOTAL / 4), dim3(256), 0, stream,
                     x, gamma, beta, Ahi, Alo);
  hipLaunchKernelGGL(gemm_fused, dim3((M_TOTAL / BM) * (NDIM / BN)), dim3(256),
                     0, stream, Ahi, Alo, Btd, bias, out);
}

// Round 4
// 251.721 us; speedup vs baseline: 1.2618x; 1.2618x over previous
//
#include <hip/hip_runtime.h>
#include <hip/hip_fp16.h>

// Problem constants (fixed by reference)
#define M_TOTAL 25088          // 128*14*14 rows
#define KDIM    384
#define NDIM    1536
#define BM      128
#define BN      128
#define BK      64
#define KSTEPS  (KDIM/BK)      // 6

typedef __attribute__((ext_vector_type(8))) _Float16 half8;
typedef __attribute__((ext_vector_type(2))) _Float16 half2v;
typedef __attribute__((ext_vector_type(2))) float   f32x2;
typedef __attribute__((ext_vector_type(4))) float   f32x4;

#define GLOAD_LDS16(g, l)                                                     \
  __builtin_amdgcn_global_load_lds(                                           \
      (const __attribute__((address_space(1))) unsigned int*)(g),             \
      (__attribute__((address_space(3))) unsigned int*)(l), 16, 0, 0)

#define LN_BLOCKS (M_TOTAL / 4)            // 6272, 4 rows/block (1 wave each)
#define PW_BLOCKS ((KDIM * NDIM) / 256)    // 2304

// ---------------------------------------------------------------------------
// Kernel 1 (fused): LayerNorm->fp16 (blocks [0,6272)) + W->Bt fp16 transpose
// (blocks [6272, 6272+2304)). Single-pass fp16: no lo parts needed.
//   Ahi[row][c] = fp16(LN(x)[row][c])
//   Bt[f][c]    = fp16(W[c][f])       (Bt is [1536][384], k-contiguous)
// ---------------------------------------------------------------------------
__global__ __launch_bounds__(256) void ln_prep(const float* __restrict__ x,
                                               const float* __restrict__ gamma,
                                               const float* __restrict__ beta,
                                               const float* __restrict__ W,
                                               _Float16* __restrict__ Ahi,
                                               _Float16* __restrict__ Bt) {
  if (blockIdx.x >= LN_BLOCKS) {
    // ---- W prep: coalesced fp32 read, scattered 2B writes (1.18 MB total)
    int idx = (blockIdx.x - LN_BLOCKS) * 256 + threadIdx.x;  // idx = c*1536+f
    int c = idx / NDIM;
    int f = idx - c * NDIM;
    Bt[(size_t)f * KDIM + c] = (_Float16)W[idx];
    return;
  }
  // ---- LayerNorm: one wave per row; lane owns col pairs {2*lane + 128*j}
  int wave = threadIdx.x >> 6;
  int lane = threadIdx.x & 63;
  int row  = blockIdx.x * 4 + wave;
  const float* xr = x + (size_t)row * KDIM;

  f32x2 v[3];
  float s = 0.f;
#pragma unroll
  for (int j = 0; j < 3; ++j) {
    v[j] = *(const f32x2*)(xr + 2 * lane + 128 * j);
    s += v[j].x + v[j].y;
  }
#pragma unroll
  for (int off = 32; off; off >>= 1) s += __shfl_xor(s, off);
  float mean = s * (1.f / 384.f);

  float s2 = 0.f;
#pragma unroll
  for (int j = 0; j < 3; ++j) {
    float dx = v[j].x - mean, dy = v[j].y - mean;
    s2 += dx * dx + dy * dy;
  }
#pragma unroll
  for (int off = 32; off; off >>= 1) s2 += __shfl_xor(s2, off);
  float rstd = rsqrtf(s2 * (1.f / 384.f) + 1e-5f);

  _Float16* hrow = Ahi + (size_t)row * KDIM;
#pragma unroll
  for (int j = 0; j < 3; ++j) {
    int c = 2 * lane + 128 * j;
    float g0 = gamma[c], g1 = gamma[c + 1];
    float b0 = beta[c],  b1 = beta[c + 1];
    half2v h;
    h.x = (_Float16)((v[j].x - mean) * rstd * g0 + b0);
    h.y = (_Float16)((v[j].y - mean) * rstd * g1 + b1);
    *(half2v*)(hrow + c) = h;
  }
}

// ---------------------------------------------------------------------------
// Kernel 2: single-pass fp16 GEMM (M=25088, N=1536, K=384) + bias + erf-GELU.
// 128x128 tile, BK=64, 4 waves (2x2, 64x64 each), mfma_f32_16x16x32_f16.
// T3-minimal 2-phase double-buffer: STAGE(next) overlaps compute(cur),
// one barrier per K-step. 16B-slot XOR swizzle c^(r&7) (rule #21:
// inverse-swizzled global source + linear LDS dest + swizzled ds_read).
// ---------------------------------------------------------------------------
__global__ __launch_bounds__(256) void gemm_fused(
    const _Float16* __restrict__ Ahi, const _Float16* __restrict__ Bt,
    const float* __restrict__ bias,   float* __restrict__ out) {
  __shared__ _Float16 Alds[2][BM * BK];   // 16 KB each
  __shared__ _Float16 Blds[2][BN * BK];

  const int tid  = threadIdx.x;
  const int lane = tid & 63;
  const int wave = tid >> 6;
  const int wr   = wave >> 1;          // 0..1
  const int wc   = wave & 1;           // 0..1

  // XCD-aware bijective swizzle: nwg = 196*12 = 2352 = 8*294
  int bidx = blockIdx.x;
  int swz  = (bidx & 7) * 294 + (bidx >> 3);
  int mb   = swz / (NDIM / BN);
  int nb   = swz - mb * (NDIM / BN);
  const int mrow0 = mb * BM;
  const int ncol0 = nb * BN;

  // --- staging constants ---
  const int rloc  = lane >> 3;                  // row within 8-row group
  const int c_swz = (lane & 7) ^ rloc;          // inverse-swizzled 16B slot
  size_t aoff[4], boff[4];
  int dsto[4];
#pragma unroll
  for (int ii = 0; ii < 4; ++ii) {
    int i = wave * 4 + ii;
    int r = i * 8 + rloc;
    aoff[ii] = (size_t)(mrow0 + r) * KDIM + (size_t)c_swz * 8;
    boff[ii] = (size_t)(ncol0 + r) * KDIM + (size_t)c_swz * 8;
    dsto[ii] = i * 512;                         // 1024 B per wave-instr, linear
  }

  // --- fragment read element offsets (within one buffer) ---
  int ea[4][2], eb[4][2];
#pragma unroll
  for (int m = 0; m < 4; ++m) {
    int r  = wr * 64 + m * 16 + (lane & 15);
    int rb = wc * 64 + m * 16 + (lane & 15);
#pragma unroll
    for (int k2 = 0; k2 < 2; ++k2) {
      int slot = k2 * 4 + (lane >> 4);
      ea[m][k2] = r  * 64 + ((slot ^ (r  & 7)) * 8);
      eb[m][k2] = rb * 64 + ((slot ^ (rb & 7)) * 8);
    }
  }

  f32x4 acc[4][4];
#pragma unroll
  for (int m = 0; m < 4; ++m)
#pragma unroll
    for (int n = 0; n < 4; ++n) acc[m][n] = (f32x4){0.f, 0.f, 0.f, 0.f};

  // --- prologue: stage step 0 into buffer 0 ---
#pragma unroll
  for (int ii = 0; ii < 4; ++ii) {
    GLOAD_LDS16(Ahi + aoff[ii], &Alds[0][dsto[ii]]);
    GLOAD_LDS16(Bt  + boff[ii], &Blds[0][dsto[ii]]);
  }
  __syncthreads();                              // drains vmcnt(0)

  // --- K loop: 6 steps, 2-phase double-buffer ---
  int cur = 0;
  for (int s6 = 0; s6 < KSTEPS; ++s6) {
    if (s6 < KSTEPS - 1) {
      const int col = (s6 + 1) * BK;
      const int nxt = cur ^ 1;
#pragma unroll
      for (int ii = 0; ii < 4; ++ii) {
        GLOAD_LDS16(Ahi + aoff[ii] + col, &Alds[nxt][dsto[ii]]);
        GLOAD_LDS16(Bt  + boff[ii] + col, &Blds[nxt][dsto[ii]]);
      }
    }
    half8 af[2][4], bf[2][4];
#pragma unroll
    for (int m = 0; m < 4; ++m) {
#pragma unroll
      for (int k2 = 0; k2 < 2; ++k2) {
        af[k2][m] = *(const half8*)&Alds[cur][ea[m][k2]];
        bf[k2][m] = *(const half8*)&Blds[cur][eb[m][k2]];
      }
    }
#pragma unroll
    for (int k2 = 0; k2 < 2; ++k2)
#pragma unroll
      for (int m = 0; m < 4; ++m)
#pragma unroll
        for (int n = 0; n < 4; ++n)
          acc[m][n] = __builtin_amdgcn_mfma_f32_16x16x32_f16(
              af[k2][m], bf[k2][n], acc[m][n], 0, 0, 0);
    __syncthreads();                            // drains vmcnt+lgkm (stage done)
    cur ^= 1;
  }

  // --- epilogue: bias + exact GELU, fp32 store ---
#pragma unroll
  for (int n = 0; n < 4; ++n) {
    int col = ncol0 + wc * 64 + n * 16 + (lane & 15);
    float bv = bias[col];
#pragma unroll
    for (int m = 0; m < 4; ++m) {
      int row = mrow0 + wr * 64 + m * 16 + ((lane >> 4) << 2);
#pragma unroll
      for (int j = 0; j < 4; ++j) {
        float y = acc[m][n][j] + bv;
        float g = 0.5f * y * (1.f + erff(y * 0.70710678118654752f));
        out[(size_t)(row + j) * NDIM + col] = g;
      }
    }
  }
}

// ---------------------------------------------------------------------------
extern "C" void kernel_launch(void* const* d_in, const int* in_sizes, int n_in,
                              void* d_out, int out_size, void* d_ws, size_t ws_size,
                              hipStream_t stream) {
  const float* x     = (const float*)d_in[0];
  const float* gamma = (const float*)d_in[1];
  const float* beta  = (const float*)d_in[2];
  const float* W     = (const float*)d_in[3];
  const float* bias  = (const float*)d_in[4];
  float* out = (float*)d_out;

  // workspace layout (bytes)
  _Float16* Ahi = (_Float16*)d_ws;                                  // 19.27 MB
  _Float16* Btd = (_Float16*)((char*)d_ws + (size_t)M_TOTAL * KDIM * 2);

  hipLaunchKernelGGL(ln_prep, dim3(LN_BLOCKS + PW_BLOCKS), dim3(256), 0,
                     stream, x, gamma, beta, W, Ahi, Btd);
  hipLaunchKernelGGL(gemm_fused, dim3((M_TOTAL / BM) * (NDIM / BN)), dim3(256),
                     0, stream, Ahi, Btd, bias, out);
}

// Round 5
// 235.371 us; speedup vs baseline: 1.3495x; 1.0695x over previous
//
#include <hip/hip_runtime.h>
#include <hip/hip_fp16.h>

// Problem constants (fixed by reference)
#define M_TOTAL 25088          // 128*14*14 rows
#define KDIM    384
#define NDIM    1536
#define BM      128
#define BN      128
#define BK      32
#define KSTEPS  (KDIM/BK)      // 12

typedef __attribute__((ext_vector_type(8))) _Float16 half8;
typedef __attribute__((ext_vector_type(2))) _Float16 half2v;
typedef __attribute__((ext_vector_type(2))) float   f32x2;
typedef __attribute__((ext_vector_type(4))) float   f32x4;

#define GLOAD_LDS16(g, l)                                                     \
  __builtin_amdgcn_global_load_lds(                                           \
      (const __attribute__((address_space(1))) unsigned int*)(g),             \
      (__attribute__((address_space(3))) unsigned int*)(l), 16, 0, 0)

#if __has_builtin(__builtin_amdgcn_rcpf)
#define RCPF(v) __builtin_amdgcn_rcpf(v)
#else
#define RCPF(v) (1.0f / (v))
#endif

#define LN_BLOCKS (M_TOTAL / 4)            // 6272, 4 rows/block (1 wave each)
#define PW_BLOCKS ((KDIM * NDIM) / 256)    // 2304

// ---------------------------------------------------------------------------
// Kernel 1 (fused): LayerNorm->fp16 (blocks [0,6272)) + W->Bt fp16 transpose
// (blocks [6272, 6272+2304)). Single-pass fp16 (validated r4: absmax 0.031).
//   Ahi[row][c] = fp16(LN(x)[row][c])
//   Bt[f][c]    = fp16(W[c][f])       (Bt is [1536][384], k-contiguous)
// ---------------------------------------------------------------------------
__global__ __launch_bounds__(256) void ln_prep(const float* __restrict__ x,
                                               const float* __restrict__ gamma,
                                               const float* __restrict__ beta,
                                               const float* __restrict__ W,
                                               _Float16* __restrict__ Ahi,
                                               _Float16* __restrict__ Bt) {
  if (blockIdx.x >= LN_BLOCKS) {
    int idx = (blockIdx.x - LN_BLOCKS) * 256 + threadIdx.x;  // idx = c*1536+f
    int c = idx / NDIM;
    int f = idx - c * NDIM;
    Bt[(size_t)f * KDIM + c] = (_Float16)W[idx];
    return;
  }
  int wave = threadIdx.x >> 6;
  int lane = threadIdx.x & 63;
  int row  = blockIdx.x * 4 + wave;
  const float* xr = x + (size_t)row * KDIM;

  f32x2 v[3];
  float s = 0.f;
#pragma unroll
  for (int j = 0; j < 3; ++j) {
    v[j] = *(const f32x2*)(xr + 2 * lane + 128 * j);
    s += v[j].x + v[j].y;
  }
#pragma unroll
  for (int off = 32; off; off >>= 1) s += __shfl_xor(s, off);
  float mean = s * (1.f / 384.f);

  float s2 = 0.f;
#pragma unroll
  for (int j = 0; j < 3; ++j) {
    float dx = v[j].x - mean, dy = v[j].y - mean;
    s2 += dx * dx + dy * dy;
  }
#pragma unroll
  for (int off = 32; off; off >>= 1) s2 += __shfl_xor(s2, off);
  float rstd = rsqrtf(s2 * (1.f / 384.f) + 1e-5f);

  _Float16* hrow = Ahi + (size_t)row * KDIM;
#pragma unroll
  for (int j = 0; j < 3; ++j) {
    int c = 2 * lane + 128 * j;
    float g0 = gamma[c], g1 = gamma[c + 1];
    float b0 = beta[c],  b1 = beta[c + 1];
    half2v h;
    h.x = (_Float16)((v[j].x - mean) * rstd * g0 + b0);
    h.y = (_Float16)((v[j].y - mean) * rstd * g1 + b1);
    *(half2v*)(hrow + c) = h;
  }
}

// ---------------------------------------------------------------------------
// Kernel 2: single-pass fp16 GEMM (M=25088, N=1536, K=384) + bias + GELU.
// 128x128 tile, BK=32 double-buffered -> 32 KB LDS -> 4 blocks/CU resident
// (occupancy lever vs r4's 64 KB / 2 blocks). 4 waves (2x2, 64x64 each),
// mfma_f32_16x16x32_f16, one barrier per K-step.
// LDS chunk permutation: chunk(row16, slot) at pos (row&15)+16*(slot^(row&3))
// within each 16-row / 1KB group -> read bank-group = row%8, balanced 2-way
// (free). Inverse permutation applied on global source (rule #21).
// Epilogue: branch-free A&S 7.1.26 erf (|eps|<=1.5e-7) instead of erff.
// ---------------------------------------------------------------------------
__global__ __launch_bounds__(256, 4) void gemm_fused(
    const _Float16* __restrict__ Ahi, const _Float16* __restrict__ Bt,
    const float* __restrict__ bias,   float* __restrict__ out) {
  __shared__ _Float16 Alds[2][BM * BK];   // 8 KB each buffer
  __shared__ _Float16 Blds[2][BN * BK];

  const int tid  = threadIdx.x;
  const int lane = tid & 63;
  const int wave = tid >> 6;
  const int wr   = wave >> 1;          // 0..1
  const int wc   = wave & 1;           // 0..1

  // XCD-aware bijective swizzle: nwg = 196*12 = 2352 = 8*294
  int bidx = blockIdx.x;
  int swz  = (bidx & 7) * 294 + (bidx >> 3);
  int mb   = swz / (NDIM / BN);
  int nb   = swz - mb * (NDIM / BN);
  const int mrow0 = mb * BM;
  const int ncol0 = nb * BN;

  // --- staging constants ---
  // Each 1KB gload_lds instr covers a 16-row group; lane l writes chunk
  // (row = l&15, slot = (l>>4)^(l&3)) of that group (inverse of read perm).
  const int srow  = lane & 15;
  const int sslot = (lane >> 4) ^ (lane & 3);
  size_t aoff[2], boff[2];
  int dsto[2];
#pragma unroll
  for (int ii = 0; ii < 2; ++ii) {
    int r = wave * 32 + ii * 16 + srow;       // tile row, this wave's 2 groups
    aoff[ii] = (size_t)(mrow0 + r) * KDIM + (size_t)sslot * 8;
    boff[ii] = (size_t)(ncol0 + r) * KDIM + (size_t)sslot * 8;
    dsto[ii] = (wave * 2 + ii) * 512;         // 1KB per instr, linear dest
  }

  // --- fragment read offsets (half-index), shared lane term ---
  const int lterm = (lane & 15) * 8 + ((lane >> 4) ^ (lane & 3)) * 128;
  int ea[4], eb[4];
#pragma unroll
  for (int m = 0; m < 4; ++m) {
    ea[m] = (wr * 64 + m * 16) * 32 + lterm;
    eb[m] = (wc * 64 + m * 16) * 32 + lterm;
  }

  f32x4 acc[4][4];
#pragma unroll
  for (int m = 0; m < 4; ++m)
#pragma unroll
    for (int n = 0; n < 4; ++n) acc[m][n] = (f32x4){0.f, 0.f, 0.f, 0.f};

  // --- prologue: stage step 0 into buffer 0 ---
#pragma unroll
  for (int ii = 0; ii < 2; ++ii) {
    GLOAD_LDS16(Ahi + aoff[ii], &Alds[0][dsto[ii]]);
    GLOAD_LDS16(Bt  + boff[ii], &Blds[0][dsto[ii]]);
  }
  __syncthreads();

  // --- K loop: 12 steps of BK=32, 2-phase double-buffer ---
  int cur = 0;
  for (int ks = 0; ks < KSTEPS; ++ks) {
    if (ks < KSTEPS - 1) {
      const int col = (ks + 1) * BK;
      const int nxt = cur ^ 1;
#pragma unroll
      for (int ii = 0; ii < 2; ++ii) {
        GLOAD_LDS16(Ahi + aoff[ii] + col, &Alds[nxt][dsto[ii]]);
        GLOAD_LDS16(Bt  + boff[ii] + col, &Blds[nxt][dsto[ii]]);
      }
    }
    half8 af[4], bf[4];
#pragma unroll
    for (int m = 0; m < 4; ++m) {
      af[m] = *(const half8*)&Alds[cur][ea[m]];
      bf[m] = *(const half8*)&Blds[cur][eb[m]];
    }
#pragma unroll
    for (int m = 0; m < 4; ++m)
#pragma unroll
      for (int n = 0; n < 4; ++n)
        acc[m][n] = __builtin_amdgcn_mfma_f32_16x16x32_f16(
            af[m], bf[n], acc[m][n], 0, 0, 0);
    __syncthreads();                          // stage(next) + reads drained
    cur ^= 1;
  }

  // --- epilogue: bias + GELU (A&S 7.1.26 erf, branch-free), fp32 store ---
#pragma unroll
  for (int n = 0; n < 4; ++n) {
    int col = ncol0 + wc * 64 + n * 16 + (lane & 15);
    float bv = bias[col];
#pragma unroll
    for (int m = 0; m < 4; ++m) {
      int row = mrow0 + wr * 64 + m * 16 + ((lane >> 4) << 2);
#pragma unroll
      for (int j = 0; j < 4; ++j) {
        float y  = acc[m][n][j] + bv;
        float ay = fabsf(y);
        float xe = ay * 0.70710678118654752f;
        float t  = RCPF(1.0f + 0.3275911f * xe);
        float p  = ((((1.061405429f * t - 1.453152027f) * t + 1.421413741f) *
                         t - 0.284496736f) * t + 0.254829592f) * t;
        float e  = 1.0f - p * __expf(-xe * xe);   // erf(|y|/sqrt(2))
        float g  = 0.5f * (y + ay * e);           // 0.5*y*(1+sign(y)*e)
        out[(size_t)(row + j) * NDIM + col] = g;
      }
    }
  }
}

// ---------------------------------------------------------------------------
extern "C" void kernel_launch(void* const* d_in, const int* in_sizes, int n_in,
                              void* d_out, int out_size, void* d_ws, size_t ws_size,
                              hipStream_t stream) {
  const float* x     = (const float*)d_in[0];
  const float* gamma = (const float*)d_in[1];
  const float* beta  = (const float*)d_in[2];
  const float* W     = (const float*)d_in[3];
  const float* bias  = (const float*)d_in[4];
  float* out = (float*)d_out;

  _Float16* Ahi = (_Float16*)d_ws;                                  // 19.27 MB
  _Float16* Btd = (_Float16*)((char*)d_ws + (size_t)M_TOTAL * KDIM * 2);

  hipLaunchKernelGGL(ln_prep, dim3(LN_BLOCKS + PW_BLOCKS), dim3(256), 0,
                     stream, x, gamma, beta, W, Ahi, Btd);
  hipLaunchKernelGGL(gemm_fused, dim3((M_TOTAL / BM) * (NDIM / BN)), dim3(256),
                     0, stream, Ahi, Btd, bias, out);
}